// Round 10
// baseline (10605.731 us; speedup 1.0000x reference)
//
#include <hip/hip_runtime.h>
#include <math.h>

// RNN with short-term plasticity: persistent cooperative kernel,
// 8 independent groups of 32 WGs (batch-partitioned), per-group barrier.
//
// Round 10: round-9 structure, but masked weights live in LDS instead of
// registers. Round 9's VGPR_Count=64 proved the allocator rematerialized
// the w[2][32] loads INSIDE the t-loop -> Whh+Wmask (8 MB chip-wide)
// restreamed from HBM every step: FETCH 6.9 MB/step at 1.16 TB/s == the
// entire 6.9 us/step runtime. wlds is remat-proof: weights are fetched
// once, per-step weight traffic is zero. Layout [jj][ks]*33+row rotates
// banks across the wave's 4 ks-subgroups (<=2-way conflicts, free).
// LDS 157 KB/WG (round 8 proved >64 KB static shared works); 1 WG/CU.
//
#define NH 1024
#define NB 32
#define NI 8
#define NO 8
#define TSTEPS 1000

#define NWG 256
#define BLK 512
#define NG 8          // independent groups
#define NM 32         // members (WGs) per group
#define GBATCH 4      // batches per group

// d_out float offsets (z, h, r, u concatenated flat)
#define OFF_Z 0
#define OFF_H (NB * TSTEPS * NO)            // 256000
#define OFF_R (OFF_H + NB * TSTEPS * NH)    // 33024000
#define OFF_U (OFF_R + NB * TSTEPS * NH)    // 65792000

// d_ws float offsets: slots 256x128B = 32 KB, then A, then ZP
#define WS_A  8192                               // A[2][NG][NH][GBATCH]
#define WS_ZP (WS_A + 2 * NG * NH * GBATCH)      // ZP[2][NG][GBATCH][NO][NM]

// wlds index: j = ks*32+jj (ks=j>>5, jj=j&31), row in [0,32)
#define WLDS_IDX(j, row) ((((j) & 31) * 32 + ((j) >> 5)) * 33 + (row))

typedef unsigned long long u64;

__device__ __forceinline__ float2 aload2(const float* p) {
    u64 v = __hip_atomic_load((const u64*)p, __ATOMIC_RELAXED,
                              __HIP_MEMORY_SCOPE_AGENT);
    return __builtin_bit_cast(float2, v);
}
__device__ __forceinline__ float aload1(const float* p) {
    return __hip_atomic_load(p, __ATOMIC_RELAXED, __HIP_MEMORY_SCOPE_AGENT);
}
__device__ __forceinline__ void astore(float* p, float v) {
    __hip_atomic_store(p, v, __ATOMIC_RELAXED, __HIP_MEMORY_SCOPE_AGENT);
}

// Per-group barrier: member m stamps slot [G][m] (128B-strided; round 7:
// packed slots serialize on shared lines); lanes<32 of wave 0 poll the
// group's slots. Release ordering: leading __syncthreads drains vmcnt in
// every wave (agent-scope stores ack'd at the coherence point) first.
__device__ __forceinline__ void groupbar(unsigned* slot, int G, int m,
                                         unsigned stamp) {
    __syncthreads();
    if (threadIdx.x == 0)
        __hip_atomic_store(&slot[(G * NM + m) * 32], stamp,
                           __ATOMIC_RELAXED, __HIP_MEMORY_SCOPE_AGENT);
    if (threadIdx.x < NM) {
        while (__hip_atomic_load(&slot[(G * NM + threadIdx.x) * 32],
                                 __ATOMIC_RELAXED, __HIP_MEMORY_SCOPE_AGENT)
               < stamp)
            __builtin_amdgcn_s_sleep(1);
    }
    __syncthreads();
}

__global__ __launch_bounds__(BLK, 2) void rnn_stp_kernel(
    const float* __restrict__ x,     // [32][1000][8]
    const float* __restrict__ h0,    // [32][1024]
    const float* __restrict__ r0,    // [32][1024]
    const float* __restrict__ u0,    // [32][1024]
    const float* __restrict__ prel,  // [1024]
    const float* __restrict__ scal,  // [1024]
    const float* __restrict__ Wih,   // [1024][8]
    const float* __restrict__ Whh,   // [1024][1024]
    const float* __restrict__ Wmask, // [1024][1024]
    const float* __restrict__ Whz,   // [8][1024]
    float* __restrict__ out,
    float* __restrict__ ws)
{
    const int tid = threadIdx.x;
    const int g   = blockIdx.x;

    // G = g&7 -> group == XCD (locality heuristic only, never correctness).
    const int G = g & 7;
    const int m = g >> 3;

    unsigned* slot = (unsigned*)ws;
    float* Abuf = ws + WS_A;    // [2][NG][NH][GBATCH]
    float* ZP   = ws + WS_ZP;   // [2][NG][GBATCH][NO][NM]

    const int ib = 32 * m;      // first of 32 owned neurons

    __shared__ float  wlds[1024 * 33];         // 132 KB masked weights
    __shared__ float4 atile[NM * 33];          // 16.9 KB A-tile (padded)
    __shared__ float  red[8 * 16 * 9];         // 4.6 KB
    __shared__ float  hbuf[GBATCH][NM];        // 512 B

    const int lane = tid & 63, wid = tid >> 6;

    // ---- stage masked weights into LDS (one-time, coalesced) ----
    {
        const int srow = tid >> 4;      // 0..31
        const int sq   = tid & 15;      // float4 slot
        const float* wp = Whh   + (ib + srow) * NH;
        const float* mp = Wmask + (ib + srow) * NH;
        #pragma unroll
        for (int p = 0; p < 16; ++p) {
            const int j4 = p * 64 + sq * 4;
            float4 wv = *(const float4*)(wp + j4);
            float4 mv = *(const float4*)(mp + j4);
            wlds[WLDS_IDX(j4 + 0, srow)] = wv.x * mv.x;
            wlds[WLDS_IDX(j4 + 1, srow)] = wv.y * mv.y;
            wlds[WLDS_IDX(j4 + 2, srow)] = wv.z * mv.z;
            wlds[WLDS_IDX(j4 + 3, srow)] = wv.w * mv.w;
        }
    }

    // ---- GEMM roles: ks = tid>>4 (j in [32ks,+32)), il = tid&15 ----
    const int ks = tid >> 4;
    const int il = tid & 15;        // owns rows 2il, 2il+1

    // ---- owner role: tid<128: local batch ob = tid>>5, neuron on = tid&31 ----
    const bool own = tid < 128;
    const int ob = tid >> 5;
    const int on = tid & 31;
    const int bglob = G * GBATCH + ob;
    const int oi = ib + on;
    float h = 0.f, r = 0.f, u = 0.f, htr = 0.f, p = 0.f, sc = 0.f;
    float wih[8];
    if (own) {
        h  = h0[bglob * NH + oi];
        r  = r0[bglob * NH + oi];
        u  = u0[bglob * NH + oi];
        p  = prel[oi];
        sc = scal[oi];
        #pragma unroll
        for (int k = 0; k < 8; ++k) wih[k] = Wih[oi * NI + k];
        htr = tanhf(h);
        astore(&Abuf[G * (NH * GBATCH) + oi * GBATCH + ob], r * sc * htr);
    }

    // ---- z-partial consts (waves 0..3): o = lane>>3, nsub = lane&7 ----
    float wzv[4];
    #pragma unroll
    for (int k = 0; k < 4; ++k)
        wzv[k] = Whz[(lane >> 3) * NH + ib + (lane & 7) + 8 * k];
    // ---- z-finalize consts (wave 4, lanes<32): member m -> (bf, of) ----
    const int bf = m >> 3, of = m & 7;

    unsigned stamp = 1;
    groupbar(slot, G, m, stamp); ++stamp;

    for (int t = 0; t < TSTEPS; ++t) {
        const int par = t & 1;

        // ---- stage A[par][G] (16 KB) into LDS; 8 floats (2 rows) each ----
        const float* Ag = Abuf + par * (NG * NH * GBATCH) + G * (NH * GBATCH);
        {
            float2 s0 = aload2(Ag + tid * 8 + 0);
            float2 s1 = aload2(Ag + tid * 8 + 2);
            float2 s2 = aload2(Ag + tid * 8 + 4);
            float2 s3 = aload2(Ag + tid * 8 + 6);
            const int r0i = tid * 2;           // rows r0i, r0i+1
            atile[r0i + (r0i >> 5)]     = make_float4(s0.x, s0.y, s1.x, s1.y);
            atile[r0i + 1 + (r0i >> 5)] = make_float4(s2.x, s2.y, s3.x, s3.y);
        }

        // ---- x prefetch for owners (cached, latency-tolerant) ----
        float4 xa = make_float4(0.f, 0.f, 0.f, 0.f), xb = xa;
        if (own) {
            const float4* xp = (const float4*)(x + (bglob * TSTEPS + t) * NI);
            xa = xp[0];
            xb = xp[1];
        }
        __syncthreads();

        // ---- GEMM: 32 j x 2 rows x 4 b; a broadcast, w from LDS ----
        float acc[2][4] = {{0.f,0.f,0.f,0.f},{0.f,0.f,0.f,0.f}};
        {
            const float4* at4 = atile + 33 * ks;
            const float*  wb  = wlds + ks * 33 + 2 * il;   // + jj*(32*33)
            #pragma unroll 8
            for (int jj = 0; jj < 32; ++jj) {
                float4 a = at4[jj];
                float2 w2 = *(const float2*)(wb + jj * (32 * 33));
                acc[0][0] = fmaf(a.x, w2.x, acc[0][0]);
                acc[0][1] = fmaf(a.y, w2.x, acc[0][1]);
                acc[0][2] = fmaf(a.z, w2.x, acc[0][2]);
                acc[0][3] = fmaf(a.w, w2.x, acc[0][3]);
                acc[1][0] = fmaf(a.x, w2.y, acc[1][0]);
                acc[1][1] = fmaf(a.y, w2.y, acc[1][1]);
                acc[1][2] = fmaf(a.z, w2.y, acc[1][2]);
                acc[1][3] = fmaf(a.w, w2.y, acc[1][3]);
            }
        }

        // ---- butterfly over ks low bits (lane bits 4,5) ----
        #pragma unroll
        for (int mm = 16; mm <= 32; mm <<= 1) {
            #pragma unroll
            for (int nn = 0; nn < 2; ++nn) {
                #pragma unroll
                for (int q = 0; q < 4; ++q)
                    acc[nn][q] += __shfl_xor(acc[nn][q], mm, 64);
            }
        }
        if (lane < 16) {
            float* rp = red + (wid * 16 + lane) * 9;
            rp[0] = acc[0][0]; rp[1] = acc[0][1];
            rp[2] = acc[0][2]; rp[3] = acc[0][3];
            rp[4] = acc[1][0]; rp[5] = acc[1][1];
            rp[6] = acc[1][2]; rp[7] = acc[1][3];
        }
        __syncthreads();

        // ---- owner: combine 8 wave partials, update state, write out ----
        if (own) {
            float rec = 0.f;
            #pragma unroll
            for (int wv = 0; wv < 8; ++wv)
                rec += red[(wv * 16 + (on >> 1)) * 9 + (on & 1) * 4 + ob];

            float xv = fmaf(xa.x, wih[0], fmaf(xa.y, wih[1],
                       fmaf(xa.z, wih[2], xa.w * wih[3])));
            xv = fmaf(xb.x, wih[4], fmaf(xb.y, wih[5],
                 fmaf(xb.z, wih[6], fmaf(xb.w, wih[7], xv))));

            float drive = 0.5f * (1.0f + htr);
            float rn = r + ((p - r) / 0.2f - 10.0f * r * drive) * 0.001f;
            float un = u + ((p - u) / 1.5f + 10.0f * (1.0f - u) * drive) * 0.001f;
            float hn = h + ((-h + xv + rec) / 0.01f) * 0.001f;
            float htn = tanhf(hn);

            out[OFF_H + (bglob * TSTEPS + t) * NH + oi] = hn;
            out[OFF_R + (bglob * TSTEPS + t) * NH + oi] = rn;
            out[OFF_U + (bglob * TSTEPS + t) * NH + oi] = un;

            astore(&Abuf[(par ^ 1) * (NG * NH * GBATCH) + G * (NH * GBATCH)
                         + oi * GBATCH + ob], rn * sc * htn);
            hbuf[ob][on] = htn;

            h = hn; r = rn; u = un; htr = htn;
        }
        __syncthreads();   // hbuf visible to z-partial waves

        // ---- z partials for step t: waves 0..3 (b = wid) ----
        if (wid < 4) {
            const int o = lane >> 3, ns = lane & 7;
            float zp = 0.f;
            #pragma unroll
            for (int k = 0; k < 4; ++k)
                zp = fmaf(hbuf[wid][ns + 8 * k], wzv[k], zp);
            zp += __shfl_xor(zp, 1, 64);
            zp += __shfl_xor(zp, 2, 64);
            zp += __shfl_xor(zp, 4, 64);
            if (ns == 0)
                astore(&ZP[par * (NG * GBATCH * NO * NM)
                           + G * (GBATCH * NO * NM)
                           + wid * (NO * NM) + o * NM + m], zp);
        }
        // ---- z finalize for step t-1: wave 4, lanes<32 ----
        if (t >= 1 && wid == 4 && lane < NM) {
            float v = aload1(ZP + (par ^ 1) * (NG * GBATCH * NO * NM)
                             + G * (GBATCH * NO * NM)
                             + bf * (NO * NM) + of * NM + lane);
            v += __shfl_xor(v, 1, 64);
            v += __shfl_xor(v, 2, 64);
            v += __shfl_xor(v, 4, 64);
            v += __shfl_xor(v, 8, 64);
            v += __shfl_xor(v, 16, 64);
            if (lane == 0)
                out[OFF_Z + ((G * GBATCH + bf) * TSTEPS + (t - 1)) * NO + of] = v;
        }

        groupbar(slot, G, m, stamp); ++stamp;
    }

    // ---- epilogue: finalize z[999] (partials in ZP[1]) ----
    if (wid == 4 && lane < NM) {
        float v = aload1(ZP + 1 * (NG * GBATCH * NO * NM)
                         + G * (GBATCH * NO * NM)
                         + bf * (NO * NM) + of * NM + lane);
        v += __shfl_xor(v, 1, 64);
        v += __shfl_xor(v, 2, 64);
        v += __shfl_xor(v, 4, 64);
        v += __shfl_xor(v, 8, 64);
        v += __shfl_xor(v, 16, 64);
        if (lane == 0)
            out[OFF_Z + ((G * GBATCH + bf) * TSTEPS + 999) * NO + of] = v;
    }
}

extern "C" void kernel_launch(void* const* d_in, const int* in_sizes, int n_in,
                              void* d_out, int out_size, void* d_ws, size_t ws_size,
                              hipStream_t stream) {
    const float* x     = (const float*)d_in[0];
    const float* h0    = (const float*)d_in[1];
    const float* r0    = (const float*)d_in[2];
    const float* u0    = (const float*)d_in[3];
    const float* prel  = (const float*)d_in[4];
    const float* scal  = (const float*)d_in[5];
    const float* Wih   = (const float*)d_in[6];
    const float* Whh   = (const float*)d_in[7];
    const float* Wmask = (const float*)d_in[8];
    const float* Whz   = (const float*)d_in[9];
    float* out = (float*)d_out;
    float* ws  = (float*)d_ws;

    // Zero the 256 barrier slots (128B apart) each launch.
    hipMemsetAsync(d_ws, 0, NWG * 128, stream);

    void* args[] = { &x, &h0, &r0, &u0, &prel, &scal,
                     &Wih, &Whh, &Wmask, &Whz, &out, &ws };
    hipLaunchCooperativeKernel((void*)rnn_stp_kernel, dim3(NWG), dim3(BLK),
                               args, 0, stream);
}

// Round 11
// 3841.730 us; speedup vs baseline: 2.7607x; 2.7607x over previous
//
#include <hip/hip_runtime.h>
#include <math.h>

// RNN with short-term plasticity: persistent cooperative kernel,
// 8 independent groups of 32 WGs (batch-partitioned), per-group barrier.
//
// Round 11: round-9 structure with the rule-#20 fix. Round 9's GEMM used
// `#pragma unroll 8` -> runtime-indexed w[nn][jj] -> the compiler
// REMATERIALIZED the masked-weight global loads inside the t-loop
// (VGPR_Count=64, FETCH 6.9 GB = 6.9 MB/step weight restream = the whole
// runtime). Round 10 moved w to LDS and fixed FETCH but serialized on
// ds_read->FMA latency at 1 WG/CU (10.6 ms). Here: FULL unroll, all
// compile-time indices -> w[2][32] register-resident (round 4 proved 64
// w-floats fit at the 128-VGPR cap), A-broadcast stays 4 MB/step, LDS
// stays 22 KB (2 WG/CU possible).
//
#define NH 1024
#define NB 32
#define NI 8
#define NO 8
#define TSTEPS 1000

#define NWG 256
#define BLK 512
#define NG 8          // independent groups
#define NM 32         // members (WGs) per group
#define GBATCH 4      // batches per group

// d_out float offsets (z, h, r, u concatenated flat)
#define OFF_Z 0
#define OFF_H (NB * TSTEPS * NO)            // 256000
#define OFF_R (OFF_H + NB * TSTEPS * NH)    // 33024000
#define OFF_U (OFF_R + NB * TSTEPS * NH)    // 65792000

// d_ws float offsets: slots 256x128B = 32 KB, then A, then ZP
#define WS_A  8192                               // A[2][NG][NH][GBATCH]
#define WS_ZP (WS_A + 2 * NG * NH * GBATCH)      // ZP[2][NG][GBATCH][NO][NM]

typedef unsigned long long u64;

__device__ __forceinline__ float2 aload2(const float* p) {
    u64 v = __hip_atomic_load((const u64*)p, __ATOMIC_RELAXED,
                              __HIP_MEMORY_SCOPE_AGENT);
    return __builtin_bit_cast(float2, v);
}
__device__ __forceinline__ float aload1(const float* p) {
    return __hip_atomic_load(p, __ATOMIC_RELAXED, __HIP_MEMORY_SCOPE_AGENT);
}
__device__ __forceinline__ void astore(float* p, float v) {
    __hip_atomic_store(p, v, __ATOMIC_RELAXED, __HIP_MEMORY_SCOPE_AGENT);
}

// Per-group barrier: member m stamps slot [G][m] (128B-strided; round 7:
// packed slots serialize on shared lines); lanes<32 of wave 0 poll the
// group's slots. Release ordering: leading __syncthreads drains vmcnt in
// every wave (agent-scope stores ack'd at the coherence point) first.
__device__ __forceinline__ void groupbar(unsigned* slot, int G, int m,
                                         unsigned stamp) {
    __syncthreads();
    if (threadIdx.x == 0)
        __hip_atomic_store(&slot[(G * NM + m) * 32], stamp,
                           __ATOMIC_RELAXED, __HIP_MEMORY_SCOPE_AGENT);
    if (threadIdx.x < NM) {
        while (__hip_atomic_load(&slot[(G * NM + threadIdx.x) * 32],
                                 __ATOMIC_RELAXED, __HIP_MEMORY_SCOPE_AGENT)
               < stamp)
            __builtin_amdgcn_s_sleep(1);
    }
    __syncthreads();
}

__global__ __launch_bounds__(BLK, 2) void rnn_stp_kernel(
    const float* __restrict__ x,     // [32][1000][8]
    const float* __restrict__ h0,    // [32][1024]
    const float* __restrict__ r0,    // [32][1024]
    const float* __restrict__ u0,    // [32][1024]
    const float* __restrict__ prel,  // [1024]
    const float* __restrict__ scal,  // [1024]
    const float* __restrict__ Wih,   // [1024][8]
    const float* __restrict__ Whh,   // [1024][1024]
    const float* __restrict__ Wmask, // [1024][1024]
    const float* __restrict__ Whz,   // [8][1024]
    float* __restrict__ out,
    float* __restrict__ ws)
{
    const int tid = threadIdx.x;
    const int g   = blockIdx.x;

    // G = g&7 -> group == XCD (locality heuristic only, never correctness).
    const int G = g & 7;
    const int m = g >> 3;

    unsigned* slot = (unsigned*)ws;
    float* Abuf = ws + WS_A;    // [2][NG][NH][GBATCH]
    float* ZP   = ws + WS_ZP;   // [2][NG][GBATCH][NO][NM]

    const int ib = 32 * m;      // first of 32 owned neurons

    // LDS: A-tile padded to 33 float4 per 32 rows (row j -> float4 j + j>>5)
    __shared__ float4 atile[NM * 33];          // 16.9 KB
    __shared__ float  red[8 * 16 * 9];         // 4.6 KB
    __shared__ float  hbuf[GBATCH][NM];        // 512 B

    const int lane = tid & 63, wid = tid >> 6;

    // ---- GEMM roles: ks = tid>>4 (j in [32ks,+32)), il = tid&15 ----
    const int ks = tid >> 4;
    const int il = tid & 15;

    // Masked weights: w[nn][jj] = Weff[32m + il + 16nn][32ks + jj]
    // FULLY static indexing everywhere (rule #20) so these 64 floats stay
    // register-resident.
    float w[2][32];
    #pragma unroll
    for (int nn = 0; nn < 2; ++nn) {
        const int row = 32 * m + il + 16 * nn;
        const float* wp = Whh   + row * NH + 32 * ks;
        const float* mp = Wmask + row * NH + 32 * ks;
        #pragma unroll
        for (int jj = 0; jj < 32; ++jj) w[nn][jj] = wp[jj] * mp[jj];
    }

    // ---- owner role: tid<128: local batch ob = tid>>5, neuron on = tid&31 ----
    const bool own = tid < 128;
    const int ob = tid >> 5;
    const int on = tid & 31;
    const int bglob = G * GBATCH + ob;
    const int oi = ib + on;
    float h = 0.f, r = 0.f, u = 0.f, htr = 0.f, p = 0.f, sc = 0.f;
    float wih[8];
    if (own) {
        h  = h0[bglob * NH + oi];
        r  = r0[bglob * NH + oi];
        u  = u0[bglob * NH + oi];
        p  = prel[oi];
        sc = scal[oi];
        #pragma unroll
        for (int k = 0; k < 8; ++k) wih[k] = Wih[oi * NI + k];
        htr = tanhf(h);
        astore(&Abuf[G * (NH * GBATCH) + oi * GBATCH + ob], r * sc * htr);
    }

    // ---- z-partial consts (waves 0..3): o = lane>>3, nsub = lane&7 ----
    float wzv[4];
    #pragma unroll
    for (int k = 0; k < 4; ++k)
        wzv[k] = Whz[(lane >> 3) * NH + ib + (lane & 7) + 8 * k];
    // ---- z-finalize consts (wave 4, lanes<32): member m -> (bf, of) ----
    const int bf = m >> 3, of = m & 7;

    unsigned stamp = 1;
    groupbar(slot, G, m, stamp); ++stamp;

    for (int t = 0; t < TSTEPS; ++t) {
        const int par = t & 1;

        // ---- stage A[par][G] (16 KB) into LDS; 8 floats (2 rows) each ----
        const float* Ag = Abuf + par * (NG * NH * GBATCH) + G * (NH * GBATCH);
        {
            float2 s0 = aload2(Ag + tid * 8 + 0);
            float2 s1 = aload2(Ag + tid * 8 + 2);
            float2 s2 = aload2(Ag + tid * 8 + 4);
            float2 s3 = aload2(Ag + tid * 8 + 6);
            const int r0i = tid * 2;           // rows r0i, r0i+1
            atile[r0i + (r0i >> 5)]     = make_float4(s0.x, s0.y, s1.x, s1.y);
            atile[r0i + 1 + (r0i >> 5)] = make_float4(s2.x, s2.y, s3.x, s3.y);
        }

        // ---- x prefetch for owners (cached, latency-tolerant) ----
        float4 xa = make_float4(0.f, 0.f, 0.f, 0.f), xb = xa;
        if (own) {
            const float4* xp = (const float4*)(x + (bglob * TSTEPS + t) * NI);
            xa = xp[0];
            xb = xp[1];
        }
        __syncthreads();

        // ---- GEMM: 32 j x 2 rows x 4 b; FULL unroll, static indices ----
        float acc[2][4] = {{0.f,0.f,0.f,0.f},{0.f,0.f,0.f,0.f}};
        {
            const float4* at4 = atile + 33 * ks;
            #pragma unroll
            for (int jj = 0; jj < 32; ++jj) {
                float4 a = at4[jj];
                const float w0 = w[0][jj], w1 = w[1][jj];
                acc[0][0] = fmaf(a.x, w0, acc[0][0]);
                acc[0][1] = fmaf(a.y, w0, acc[0][1]);
                acc[0][2] = fmaf(a.z, w0, acc[0][2]);
                acc[0][3] = fmaf(a.w, w0, acc[0][3]);
                acc[1][0] = fmaf(a.x, w1, acc[1][0]);
                acc[1][1] = fmaf(a.y, w1, acc[1][1]);
                acc[1][2] = fmaf(a.z, w1, acc[1][2]);
                acc[1][3] = fmaf(a.w, w1, acc[1][3]);
            }
        }

        // ---- butterfly over ks low bits (lane bits 4,5) ----
        #pragma unroll
        for (int mm = 16; mm <= 32; mm <<= 1) {
            #pragma unroll
            for (int nn = 0; nn < 2; ++nn) {
                #pragma unroll
                for (int q = 0; q < 4; ++q)
                    acc[nn][q] += __shfl_xor(acc[nn][q], mm, 64);
            }
        }
        if (lane < 16) {
            float* rp = red + (wid * 16 + lane) * 9;
            rp[0] = acc[0][0]; rp[1] = acc[0][1];
            rp[2] = acc[0][2]; rp[3] = acc[0][3];
            rp[4] = acc[1][0]; rp[5] = acc[1][1];
            rp[6] = acc[1][2]; rp[7] = acc[1][3];
        }
        __syncthreads();

        // ---- owner: combine 8 wave partials, update state, write out ----
        if (own) {
            float rec = 0.f;
            #pragma unroll
            for (int wv = 0; wv < 8; ++wv)
                rec += red[(wv * 16 + (on & 15)) * 9 + (on >> 4) * 4 + ob];

            float xv = fmaf(xa.x, wih[0], fmaf(xa.y, wih[1],
                       fmaf(xa.z, wih[2], xa.w * wih[3])));
            xv = fmaf(xb.x, wih[4], fmaf(xb.y, wih[5],
                 fmaf(xb.z, wih[6], fmaf(xb.w, wih[7], xv))));

            float drive = 0.5f * (1.0f + htr);
            float rn = r + ((p - r) / 0.2f - 10.0f * r * drive) * 0.001f;
            float un = u + ((p - u) / 1.5f + 10.0f * (1.0f - u) * drive) * 0.001f;
            float hn = h + ((-h + xv + rec) / 0.01f) * 0.001f;
            float htn = tanhf(hn);

            out[OFF_H + (bglob * TSTEPS + t) * NH + oi] = hn;
            out[OFF_R + (bglob * TSTEPS + t) * NH + oi] = rn;
            out[OFF_U + (bglob * TSTEPS + t) * NH + oi] = un;

            astore(&Abuf[(par ^ 1) * (NG * NH * GBATCH) + G * (NH * GBATCH)
                         + oi * GBATCH + ob], rn * sc * htn);
            hbuf[ob][on] = htn;

            h = hn; r = rn; u = un; htr = htn;
        }
        __syncthreads();   // hbuf visible to z-partial waves

        // ---- z partials for step t: waves 0..3 (b = wid) ----
        if (wid < 4) {
            const int o = lane >> 3, ns = lane & 7;
            float zp = 0.f;
            #pragma unroll
            for (int k = 0; k < 4; ++k)
                zp = fmaf(hbuf[wid][ns + 8 * k], wzv[k], zp);
            zp += __shfl_xor(zp, 1, 64);
            zp += __shfl_xor(zp, 2, 64);
            zp += __shfl_xor(zp, 4, 64);
            if (ns == 0)
                astore(&ZP[par * (NG * GBATCH * NO * NM)
                           + G * (GBATCH * NO * NM)
                           + wid * (NO * NM) + o * NM + m], zp);
        }
        // ---- z finalize for step t-1: wave 4, lanes<32 ----
        if (t >= 1 && wid == 4 && lane < NM) {
            float v = aload1(ZP + (par ^ 1) * (NG * GBATCH * NO * NM)
                             + G * (GBATCH * NO * NM)
                             + bf * (NO * NM) + of * NM + lane);
            v += __shfl_xor(v, 1, 64);
            v += __shfl_xor(v, 2, 64);
            v += __shfl_xor(v, 4, 64);
            v += __shfl_xor(v, 8, 64);
            v += __shfl_xor(v, 16, 64);
            if (lane == 0)
                out[OFF_Z + ((G * GBATCH + bf) * TSTEPS + (t - 1)) * NO + of] = v;
        }

        groupbar(slot, G, m, stamp); ++stamp;
    }

    // ---- epilogue: finalize z[999] (partials in ZP[1]) ----
    if (wid == 4 && lane < NM) {
        float v = aload1(ZP + 1 * (NG * GBATCH * NO * NM)
                         + G * (GBATCH * NO * NM)
                         + bf * (NO * NM) + of * NM + lane);
        v += __shfl_xor(v, 1, 64);
        v += __shfl_xor(v, 2, 64);
        v += __shfl_xor(v, 4, 64);
        v += __shfl_xor(v, 8, 64);
        v += __shfl_xor(v, 16, 64);
        if (lane == 0)
            out[OFF_Z + ((G * GBATCH + bf) * TSTEPS + 999) * NO + of] = v;
    }
}

extern "C" void kernel_launch(void* const* d_in, const int* in_sizes, int n_in,
                              void* d_out, int out_size, void* d_ws, size_t ws_size,
                              hipStream_t stream) {
    const float* x     = (const float*)d_in[0];
    const float* h0    = (const float*)d_in[1];
    const float* r0    = (const float*)d_in[2];
    const float* u0    = (const float*)d_in[3];
    const float* prel  = (const float*)d_in[4];
    const float* scal  = (const float*)d_in[5];
    const float* Wih   = (const float*)d_in[6];
    const float* Whh   = (const float*)d_in[7];
    const float* Wmask = (const float*)d_in[8];
    const float* Whz   = (const float*)d_in[9];
    float* out = (float*)d_out;
    float* ws  = (float*)d_ws;

    // Zero the 256 barrier slots (128B apart) each launch.
    hipMemsetAsync(d_ws, 0, NWG * 128, stream);

    void* args[] = { &x, &h0, &r0, &u0, &prel, &scal,
                     &Wih, &Whh, &Wmask, &Whz, &out, &ws };
    hipLaunchCooperativeKernel((void*)rnn_stp_kernel, dim3(NWG), dim3(BLK),
                               args, 0, stream);
}